// Round 10
// baseline (215.479 us; speedup 1.0000x reference)
//
#include <hip/hip_runtime.h>
#include <stdint.h>

#define N_SPK 2048
#define M_UTT 16
#define D_EMB 512
#define NM (N_SPK * M_UTT)
#define FP8_SCALE 16.0f   // quantization scale for fp8 operands (1/256 folded into w)

typedef __attribute__((ext_vector_type(4))) float f32x4;
typedef __attribute__((ext_vector_type(8))) int   i32x8;

// ---------------------------------------------------------------------------
// Kernel A: per-speaker prep (r6 version — best measured). 256 thr/block,
// thread t owns dims {2t, 2t+1}. Single global pass; outputs fp8 e4m3 at
// x16 scale. dterm fp32-exact. Folds colsum/out zeroing.
// ---------------------------------------------------------------------------
__global__ __launch_bounds__(256) void prep_kernel(
    const float* __restrict__ V, const float* __restrict__ wp,
    const float* __restrict__ bp, unsigned char* __restrict__ Cn8,
    unsigned char* __restrict__ vn8, float* __restrict__ dterm,
    float* __restrict__ colsum, float* __restrict__ out)
{
    const int spk = blockIdx.x, t = threadIdx.x;
    const int wave = t >> 6, lane = t & 63;
    const float2* vb = (const float2*)(V + (size_t)spk * (M_UTT * D_EMB)); // [16][256]

    __shared__ __align__(16) float red[32][264];  // rows 0..15 sv, 16..31 vv (+8 pad)
    __shared__ float red2[32];
    __shared__ float invs[M_UTT];
    __shared__ float wred[4];

    // folded zeroing of colsum + out
    if (spk < 128) colsum[spk * 256 + t] = 0.f;
    if (spk == 0 && t == 0) out[0] = 0.f;

    // ---- single global read pass ----
    float2 p[M_UTT];
#pragma unroll
    for (int m = 0; m < M_UTT; ++m) p[m] = vb[m * 256 + t];

    float2 ss = make_float2(0.f, 0.f);
#pragma unroll
    for (int m = 0; m < M_UTT; ++m) { ss.x += p[m].x; ss.y += p[m].y; }

    // ||ssum||^2 butterfly (4 waves -> wred)
    float cnp = ss.x * ss.x + ss.y * ss.y;
#pragma unroll
    for (int off = 32; off > 0; off >>= 1) cnp += __shfl_xor(cnp, off);
    if (lane == 0) wred[wave] = cnp;

    // per-utterance partials -> LDS
#pragma unroll
    for (int m = 0; m < M_UTT; ++m) {
        red[m][t]         = ss.x * p[m].x + ss.y * p[m].y;          // <ssum, v> part
        red[m + M_UTT][t] = p[m].x * p[m].x + p[m].y * p[m].y;      // ||v||^2 part
    }
    __syncthreads();
    const float cn2 = wred[0] + wred[1] + wred[2] + wred[3];

    // ---- batched row reduction: 8 threads per row, 8 float4 each ----
    {
        const int r = t >> 3, s = t & 7;
        const float4* rp = (const float4*)red;   // row stride = 66 float4
        float4 a = make_float4(0.f, 0.f, 0.f, 0.f);
#pragma unroll
        for (int k = 0; k < 8; ++k) {
            float4 q = rp[r * 66 + s + 8 * k];
            a.x += q.x; a.y += q.y; a.z += q.z; a.w += q.w;
        }
        float v1 = (a.x + a.y) + (a.z + a.w);
        v1 += __shfl_xor(v1, 1);
        v1 += __shfl_xor(v1, 2);
        v1 += __shfl_xor(v1, 4);
        if (s == 0) red2[r] = v1;
    }
    __syncthreads();

    // ---- per-utterance scalars (fp32-exact leave-one-out sims) ----
    if (t < M_UTT) {
        const float sv = red2[t], vv = red2[t + M_UTT];
        const float cc = cn2 - 2.f * sv + vv;      // ||ssum - v||^2
        const float cv = sv - vv;                  // <ssum - v, v>
        const float dc = fmaxf(sqrtf(fmaxf(cc, 0.f)) * (1.f / (M_UTT - 1)), 1e-8f) * (M_UTT - 1);
        const float dv = fmaxf(sqrtf(vv), 1e-8f);
        dterm[spk * M_UTT + t] = (*wp) * (cv / (dc * dv)) + (*bp);
        invs[t] = FP8_SCALE / dv;
    }
    __syncthreads();

    // ---- fp8 outputs (x16 scale) ----
    const float cs = FP8_SCALE / (M_UTT * fmaxf(sqrtf(cn2) * (1.f / M_UTT), 1e-8f));
    {
        int pk = __builtin_amdgcn_cvt_pk_fp8_f32(ss.x * cs, ss.y * cs, 0, false);
        ((unsigned short*)(Cn8 + (size_t)spk * D_EMB))[t] = (unsigned short)pk;
    }
#pragma unroll
    for (int m = 0; m < M_UTT; ++m) {
        const float iv = invs[m];
        int pk = __builtin_amdgcn_cvt_pk_fp8_f32(p[m].x * iv, p[m].y * iv, 0, false);
        ((unsigned short*)(vn8 + ((size_t)(spk * M_UTT + m)) * D_EMB))[t] = (unsigned short)pk;
    }
}

// ---------------------------------------------------------------------------
// Kernel B: LDS-FREE MX-scaled fp8 GEMM. Fragments are loaded straight from
// global (L1/L2-resident thanks to XCD decode; FETCH=12.4 MB measured r9)
// into registers — per lane one contiguous 32B chunk per fragment, i.e. 16
// dense 128B segments per wave-load. ZERO __syncthreads in the K-loop: the
// 2-barrier staged-LDS structure (pinned at 55-59us across 4 variants with
// MFMA busy only ~13.6us) is replaced by compiler-scheduled vmcnt waits.
// 128x128 tile, 4 waves of 64x64 = 4x4 K=128 scaled MFMA, 4 K-windows; each
// window's A+B slice = 32 KB ~= L1, giving natural L1 blocking.
// Epilogue (exp2 + same-speaker mask + column reduce) unchanged.
// ---------------------------------------------------------------------------
__global__ __launch_bounds__(256) void gemm_kernel(
    const unsigned char* __restrict__ Cn8, const unsigned char* __restrict__ vn8,
    const float* __restrict__ wp, const float* __restrict__ bp,
    float* __restrict__ colsum)
{
    __shared__ float csum[128];

    const int tid = threadIdx.x;
    const int w = tid >> 6, l = tid & 63;
    // XCD-aware decode (r9, proven): d&7 = XCD slot; each XCD owns 32
    // consecutive bx columns x all 16 by (3 MB working set < 4 MB L2/XCD).
    const int d = blockIdx.x;
    const int xcd = d & 7, s = d >> 3;
    const int bx = xcd * 32 + (s >> 4);   // utterance tile [0,256)
    const int by = s & 15;                // speaker tile   [0,16)
    // fold log2(e): exp(w*S+b) = exp2(w2*S + b2)
    const float wgt2 = (*wp) * (1.44269504f / (FP8_SCALE * FP8_SCALE));
    const float bsc2 = (*bp) * 1.44269504f;

    if (tid < 128) csum[tid] = 0.f;
    __syncthreads();   // csum visible before epilogue atomics (only barrier pre-epilogue)

    // compute geometry: 2x2 wave grid, each wave 64x64 = 4x4 MFMA (K=128).
    // A operand for 16x16x128: lane row = l16, k-chunk = quad*32 within the
    // 128-wide window -> one 32B contiguous global segment per lane.
    const int wm = w & 1, wn = w >> 1;
    const int l16 = l & 15, q = l >> 4;
    const unsigned char* Arow = Cn8 + (size_t)(by * 128 + wm * 64 + l16) * D_EMB + q * 32;
    const unsigned char* Brow = vn8 + (size_t)(bx * 128 + wn * 64 + l16) * D_EMB + q * 32;

    f32x4 acc[4][4];
    const f32x4 z = {0.f, 0.f, 0.f, 0.f};
#pragma unroll
    for (int i = 0; i < 4; ++i)
#pragma unroll
        for (int j = 0; j < 4; ++j) acc[i][j] = z;

#pragma unroll
    for (int kk = 0; kk < D_EMB; kk += 128) {
        i32x8 af[4], bf[4];
#pragma unroll
        for (int i = 0; i < 4; ++i)
            af[i] = *(const i32x8*)(Arow + (size_t)(i * 16) * D_EMB + kk);
#pragma unroll
        for (int j = 0; j < 4; ++j)
            bf[j] = *(const i32x8*)(Brow + (size_t)(j * 16) * D_EMB + kk);
#pragma unroll
        for (int i = 0; i < 4; ++i)
#pragma unroll
            for (int j = 0; j < 4; ++j)
                acc[i][j] = __builtin_amdgcn_mfma_scale_f32_16x16x128_f8f6f4(
                    af[i], bf[j], acc[i][j], 0, 0, 0, 0x7F7F7F7F, 0, 0x7F7F7F7F);
    }

    // epilogue: e = exp2(w2*dot+b2), zero same-speaker entries, reduce rows.
    // C/D layout (shape-determined): row = q*4 + r, col = l16.
    const int rowg0 = by * 128 + wm * 64 + q * 4;
    const int colg0 = bx * 128 + wn * 64 + l16;
#pragma unroll
    for (int j = 0; j < 4; ++j) {
        const int colg = colg0 + j * 16;
        const int cspk = colg >> 4;       // speaker owning this column
        float p = 0.f;
#pragma unroll
        for (int i = 0; i < 4; ++i) {
            const int rowg = rowg0 + i * 16;
#pragma unroll
            for (int r = 0; r < 4; ++r) {
                float e = exp2f(fmaf(wgt2, acc[i][j][r], bsc2));
                p += (rowg + r == cspk) ? 0.f : e;
            }
        }
        p += __shfl_xor(p, 16);
        p += __shfl_xor(p, 32);
        if (q == 0) atomicAdd(&csum[wn * 64 + j * 16 + l16], p);
    }
    __syncthreads();
    if (tid < 128) atomicAdd(&colsum[bx * 128 + tid], csum[tid]);
}

// ---------------------------------------------------------------------------
// Kernel C: L_j = -dterm_j + log(colsum_j + exp(dterm_j)); sum -> out[0]
// ---------------------------------------------------------------------------
__global__ __launch_bounds__(256) void finish_kernel(
    const float* __restrict__ dterm, const float* __restrict__ colsum,
    float* __restrict__ out)
{
    const int idx = blockIdx.x * 256 + threadIdx.x;
    const int stride = gridDim.x * 256;
    float local = 0.f;
    for (int j = idx; j < NM; j += stride) {
        float t = dterm[j];
        local += logf(colsum[j] + __expf(t)) - t;
    }
#pragma unroll
    for (int off = 32; off > 0; off >>= 1) local += __shfl_xor(local, off);
    __shared__ float wr[4];
    const int wave = threadIdx.x >> 6, lane = threadIdx.x & 63;
    if (lane == 0) wr[wave] = local;
    __syncthreads();
    if (threadIdx.x == 0) atomicAdd(out, wr[0] + wr[1] + wr[2] + wr[3]);
}

extern "C" void kernel_launch(void* const* d_in, const int* in_sizes, int n_in,
                              void* d_out, int out_size, void* d_ws, size_t ws_size,
                              hipStream_t stream) {
    const float* V  = (const float*)d_in[0];
    const float* wp = (const float*)d_in[1];
    const float* bp = (const float*)d_in[2];

    char* ws = (char*)d_ws;
    unsigned char* Cn8 = (unsigned char*)ws;                        //  1 MB [2048][512] fp8
    unsigned char* vn8 = (unsigned char*)(ws + ((size_t)1 << 20));  // 16 MB [32768][512] fp8
    float* dterm  = (float*)(ws + ((size_t)17 << 20));              // 128 KB
    float* colsum = dterm + NM;                                     // 128 KB
    float* out    = (float*)d_out;

    prep_kernel<<<N_SPK, 256, 0, stream>>>(V, wp, bp, Cn8, vn8, dterm, colsum, out);
    gemm_kernel<<<4096, 256, 0, stream>>>(Cn8, vn8, wp, bp, colsum);
    finish_kernel<<<64, 256, 0, stream>>>(dterm, colsum, out);
}